// Round 12
// baseline (82.246 us; speedup 1.0000x reference)
//
#include <hip/hip_runtime.h>

#define DIM   4096
#define RANK  16
#define BM    16     // rows per tile = MFMA M
#define TPB   2      // tiles per block (32 rows)
#define NT    1024   // 16 waves
#define NWAVE 16

typedef __fp16 f16;
typedef __fp16 half4 __attribute__((ext_vector_type(4)));
typedef __fp16 half8 __attribute__((ext_vector_type(8)));
typedef float  floatx4 __attribute__((ext_vector_type(4)));

#define SCHED_FENCE() __builtin_amdgcn_sched_barrier(0)

// ---- prep: weights in exact MFMA fragment order (proven R5-R11) ----
// Ub[kb][l][e] = nw[k]*U[k][l&15],  k = kb*32 + (l>>4)*8 + e   (128 KB)
// Vb[cb][l][e] = V[(l>>4)*4 + e][cb*16 + (l&15)]               (128 KB)
__global__ __launch_bounds__(256) void prep_weights(const float* __restrict__ U,
    const float* __restrict__ nw, const float* __restrict__ V,
    f16* __restrict__ Ub, f16* __restrict__ Vb)
{
    const int i   = blockIdx.x * 256 + threadIdx.x;   // 0..16383
    const int l   = i & 63;
    const int n   = l & 15;
    const int blk = l >> 4;
    if (i < 8192) {                     // Ub: 128 kb-steps x 64 lanes
        const int kb = i >> 6;
        half8 u;
        #pragma unroll
        for (int e = 0; e < 8; ++e) {
            const int k = kb * 32 + blk * 8 + e;
            u[e] = (f16)(nw[k] * U[(size_t)k * RANK + n]);
        }
        *(half8*)(Ub + (size_t)i * 8) = u;
    }
    {                                   // Vb: 256 col-blocks x 64 lanes
        const int cb = i >> 6;
        half4 v;
        #pragma unroll
        for (int e = 0; e < 4; ++e) {
            const int k = blk * 4 + e;
            v[e] = (f16)V[(size_t)k * DIM + cb * 16 + n];
        }
        *(half4*)(Vb + (size_t)i * 4) = v;
    }
}

// ---- fused 2-tile pipeline ----
// A(0) -> combine(0) -> [A(1) || B(0) same-wave interleave] -> combine(1) -> B(1)
// The interleaved loop issues x-reads and out-writes from the same instruction
// stream: chip-wide HBM sees concurrent read+write streams (the copy pattern),
// instead of the serial read-epoch/write-epoch of R5-R10.
__global__ __launch_bounds__(NT, 4) void arl_fused(
    const float* __restrict__ x,  const f16* __restrict__ Ub,
    const f16* __restrict__ Vb,   const float* __restrict__ S,
    const float* __restrict__ gamma, float* __restrict__ out)
{
    const int t   = threadIdx.x;
    const int w   = t >> 6;     // 0..15
    const int l   = t & 63;
    const int n   = l & 15;     // A-frag row / D-frag col(=out row)
    const int blk = l >> 4;     // k-block / D row-group(=out col sub)
    const size_t rowB = (size_t)blockIdx.x * (BM * TPB);

    __shared__ float s_hacc[NWAVE][16][17];     // 17.4 KB (+1 pad)
    __shared__ float s_ssq[NWAVE][16];          // 1 KB
    __shared__ __align__(8) f16 s_hh[TPB][16][16];

    const half4* Vb4 = (const half4*)Vb;
    const floatx4 zero = {0.f, 0.f, 0.f, 0.f};

    // per-tile A-source base: row (tileRow+n), k-slice [w*256, +256), sub blk*8
    const float* xlaneT0 = x + (rowB + n) * DIM + w * 256 + blk * 8;
    const float* xlaneT1 = xlaneT0 + (size_t)BM * DIM;
    const f16*   UbW     = Ub + ((size_t)(w * 8) * 64 + l) * 8;  // wave's 8 kb

    floatx4 acc = {0.f, 0.f, 0.f, 0.f};
    float ssq = 0.f;

    // ================= step 1: A(tile 0), 8 kb-steps =================
    #pragma unroll
    for (int i = 0; i < 8; ++i) {
        const float4 xa0 = *(const float4*)(xlaneT0 + i * 32);
        const float4 xa1 = *(const float4*)(xlaneT0 + i * 32 + 4);
        const half8  ub  = *(const half8*)(UbW + (size_t)i * 512);
        ssq = fmaf(xa0.x, xa0.x, ssq); ssq = fmaf(xa0.y, xa0.y, ssq);
        ssq = fmaf(xa0.z, xa0.z, ssq); ssq = fmaf(xa0.w, xa0.w, ssq);
        ssq = fmaf(xa1.x, xa1.x, ssq); ssq = fmaf(xa1.y, xa1.y, ssq);
        ssq = fmaf(xa1.z, xa1.z, ssq); ssq = fmaf(xa1.w, xa1.w, ssq);
        half8 a;
        a[0] = (f16)xa0.x; a[1] = (f16)xa0.y; a[2] = (f16)xa0.z; a[3] = (f16)xa0.w;
        a[4] = (f16)xa1.x; a[5] = (f16)xa1.y; a[6] = (f16)xa1.z; a[7] = (f16)xa1.w;
        acc = __builtin_amdgcn_mfma_f32_16x16x32_f16(a, ub, acc, 0, 0, 0);
    }
    {   // spill tile-0 partials
        float sq = ssq;
        sq += __shfl_xor(sq, 16, 64);
        sq += __shfl_xor(sq, 32, 64);
        if (l < 16) s_ssq[w][l] = sq;
        #pragma unroll
        for (int j = 0; j < 4; ++j) s_hacc[w][blk * 4 + j][n] = acc[j];
    }
    __syncthreads();

    // ================= step 2: combine(tile 0) =================
    if (t < 256) {
        const int m = t >> 4, q = t & 15;
        float hsum = 0.f, tssq = 0.f;
        #pragma unroll
        for (int ww = 0; ww < NWAVE; ++ww) {
            hsum += s_hacc[ww][m][q];
            tssq += s_ssq[ww][m];
        }
        const float rstd = rsqrtf(tssq * (1.0f / DIM) + 1e-6f);
        float tot = 0.f;
        #pragma unroll
        for (int i = 0; i < RANK; ++i) tot += fabsf(S[i]);
        const float denom = fmaxf(tot, 1e-8f);
        float cum = 0.f, se = 0.f;
        #pragma unroll
        for (int i = 0; i < RANK; ++i) {
            if (i == q) se = ((cum / denom) < 0.95f) ? S[i] : 0.f;
            cum += fabsf(S[i]);
        }
        s_hh[0][m][q] = (f16)(hsum * se * rstd);
    }
    __syncthreads();

    // ================= step 3: A(tile 1) || B(tile 0), interleaved =========
    acc[0] = 0.f; acc[1] = 0.f; acc[2] = 0.f; acc[3] = 0.f;
    ssq = 0.f;
    {
        const half4 ah0  = *(const half4*)&s_hh[0][n][blk * 4];
        const float* xrow0 = x   + (rowB + n) * DIM;       // tile-0 residual (L3)
        float*       orow0 = out + (rowB + n) * DIM;

        #pragma unroll 1
        for (int i = 0; i < 8; ++i) {
            // ---- A-loads for tile 1 (issue first, consume last) ----
            const float4 xa0 = *(const float4*)(xlaneT1 + i * 32);
            const float4 xa1 = *(const float4*)(xlaneT1 + i * 32 + 4);
            const half8  ub  = *(const half8*)(UbW + (size_t)i * 512);
            SCHED_FENCE();          // pin the issue point: B-work goes below

            // ---- B for tile 0: 2 col-blocks (independent of A-loads) ----
            #pragma unroll
            for (int c = 0; c < 2; ++c) {
                const int cb = w * 16 + 2 * i + c;
                const int c0 = cb * 16 + blk * 4;
                const half4 bv = Vb4[(size_t)cb * 64 + l];
                floatx4 d = __builtin_amdgcn_mfma_f32_16x16x16f16(bv, ah0, zero, 0, 0, 0);
                const float4 g  = *(const float4*)(gamma + c0);
                const float4 xv = *(const float4*)(xrow0 + c0);
                floatx4 o;
                o[0] = fmaf(g.x, d[0], xv.x);
                o[1] = fmaf(g.y, d[1], xv.y);
                o[2] = fmaf(g.z, d[2], xv.z);
                o[3] = fmaf(g.w, d[3], xv.w);
                __builtin_nontemporal_store(o, (floatx4*)(orow0 + c0));
            }

            // ---- A-compute for tile 1 (waitcnt lands here, after B-work) ----
            ssq = fmaf(xa0.x, xa0.x, ssq); ssq = fmaf(xa0.y, xa0.y, ssq);
            ssq = fmaf(xa0.z, xa0.z, ssq); ssq = fmaf(xa0.w, xa0.w, ssq);
            ssq = fmaf(xa1.x, xa1.x, ssq); ssq = fmaf(xa1.y, xa1.y, ssq);
            ssq = fmaf(xa1.z, xa1.z, ssq); ssq = fmaf(xa1.w, xa1.w, ssq);
            half8 a;
            a[0] = (f16)xa0.x; a[1] = (f16)xa0.y; a[2] = (f16)xa0.z; a[3] = (f16)xa0.w;
            a[4] = (f16)xa1.x; a[5] = (f16)xa1.y; a[6] = (f16)xa1.z; a[7] = (f16)xa1.w;
            acc = __builtin_amdgcn_mfma_f32_16x16x32_f16(a, ub, acc, 0, 0, 0);
        }
    }
    {   // spill tile-1 partials
        float sq = ssq;
        sq += __shfl_xor(sq, 16, 64);
        sq += __shfl_xor(sq, 32, 64);
        if (l < 16) s_ssq[w][l] = sq;
    }
    __syncthreads();    // combine(0) readers done long ago; safe to overwrite
    #pragma unroll
    for (int j = 0; j < 4; ++j) s_hacc[w][blk * 4 + j][n] = acc[j];
    __syncthreads();

    // ================= step 4: combine(tile 1) =================
    if (t < 256) {
        const int m = t >> 4, q = t & 15;
        float hsum = 0.f, tssq = 0.f;
        #pragma unroll
        for (int ww = 0; ww < NWAVE; ++ww) {
            hsum += s_hacc[ww][m][q];
            tssq += s_ssq[ww][m];
        }
        const float rstd = rsqrtf(tssq * (1.0f / DIM) + 1e-6f);
        float tot = 0.f;
        #pragma unroll
        for (int i = 0; i < RANK; ++i) tot += fabsf(S[i]);
        const float denom = fmaxf(tot, 1e-8f);
        float cum = 0.f, se = 0.f;
        #pragma unroll
        for (int i = 0; i < RANK; ++i) {
            if (i == q) se = ((cum / denom) < 0.95f) ? S[i] : 0.f;
            cum += fabsf(S[i]);
        }
        s_hh[1][m][q] = (f16)(hsum * se * rstd);
    }
    __syncthreads();

    // ================= step 5: B(tile 1), 16 col-blocks =================
    {
        const half4 ah1  = *(const half4*)&s_hh[1][n][blk * 4];
        const float* xrow1 = x   + (rowB + BM + n) * DIM;  // L3-hot
        float*       orow1 = out + (rowB + BM + n) * DIM;
        #pragma unroll 4
        for (int i = 0; i < 16; ++i) {
            const int cb = w * 16 + i;
            const int c0 = cb * 16 + blk * 4;
            const half4 bv = Vb4[(size_t)cb * 64 + l];
            floatx4 d = __builtin_amdgcn_mfma_f32_16x16x16f16(bv, ah1, zero, 0, 0, 0);
            const float4 g  = *(const float4*)(gamma + c0);
            const float4 xv = *(const float4*)(xrow1 + c0);
            floatx4 o;
            o[0] = fmaf(g.x, d[0], xv.x);
            o[1] = fmaf(g.y, d[1], xv.y);
            o[2] = fmaf(g.z, d[2], xv.z);
            o[3] = fmaf(g.w, d[3], xv.w);
            __builtin_nontemporal_store(o, (floatx4*)(orow1 + c0));
        }
    }
}

extern "C" void kernel_launch(void* const* d_in, const int* in_sizes, int n_in,
                              void* d_out, int out_size, void* d_ws, size_t ws_size,
                              hipStream_t stream) {
    (void)in_sizes; (void)n_in; (void)ws_size;
    const float* x  = (const float*)d_in[0];
    const float* U  = (const float*)d_in[1];
    const float* S  = (const float*)d_in[2];
    const float* V  = (const float*)d_in[3];
    const float* nw = (const float*)d_in[4];
    const float* g  = (const float*)d_in[5];
    float* out = (float*)d_out;
    f16* Ub = (f16*)d_ws;                          // 128 KB fragment-order U'
    f16* Vb = (f16*)((char*)d_ws + 128 * 1024);    // 128 KB fragment-order V

    hipLaunchKernelGGL(prep_weights, dim3(64), dim3(256), 0, stream,
                       U, nw, V, Ub, Vb);

    const int rows = out_size / DIM;               // 8192
    const int grid = rows / (BM * TPB);            // 256
    hipLaunchKernelGGL(arl_fused, dim3(grid), dim3(NT), 0, stream,
                       x, Ub, Vb, S, g, out);
}

// Round 13
// 73.175 us; speedup vs baseline: 1.1240x; 1.1240x over previous
//
#include <hip/hip_runtime.h>

#define DIM   4096
#define RANK  16
#define BM    16     // rows per block = MFMA M
#define NT    512    // 8 waves
#define NWAVE 8
#define KSLICE (DIM/NWAVE)   // 512 k per wave in phase A
#define NKB   (KSLICE/32)    // 16 MFMA K-steps per wave
#define NCB   (DIM/16/NWAVE) // 32 out col-blocks per wave in phase B

typedef __fp16 f16;
typedef __fp16 half4 __attribute__((ext_vector_type(4)));
typedef __fp16 half8 __attribute__((ext_vector_type(8)));
typedef float  floatx4 __attribute__((ext_vector_type(4)));

// ---- prep: weights in exact MFMA fragment order ----
// A/B fragment mapping (16x16xK): lane&15 = row(A)/col(B), lane>>4 = k-block.
// Ub[kb][l][e] = nw[k]*U[k][l&15],          k = kb*32 + (l>>4)*8 + e   (128 KB)
// Vb[cb][l][e] = V[(l>>4)*4 + e][cb*16+l&15]                           (128 KB)
__global__ __launch_bounds__(256) void prep_weights(const float* __restrict__ U,
    const float* __restrict__ nw, const float* __restrict__ V,
    f16* __restrict__ Ub, f16* __restrict__ Vb)
{
    const int i   = blockIdx.x * 256 + threadIdx.x;   // 0..16383
    const int l   = i & 63;
    const int n   = l & 15;
    const int blk = l >> 4;
    if (i < 8192) {                     // Ub: 128 kb-steps x 64 lanes
        const int kb = i >> 6;
        half8 u;
        #pragma unroll
        for (int e = 0; e < 8; ++e) {
            const int k = kb * 32 + blk * 8 + e;
            u[e] = (f16)(nw[k] * U[(size_t)k * RANK + n]);
        }
        *(half8*)(Ub + (size_t)i * 8) = u;      // 16 B coalesced
    }
    {                                   // Vb: 256 col-blocks x 64 lanes
        const int cb = i >> 6;
        half4 v;
        #pragma unroll
        for (int e = 0; e < 4; ++e) {
            const int k = blk * 4 + e;
            v[e] = (f16)V[(size_t)k * DIM + cb * 16 + n];
        }
        *(half4*)(Vb + (size_t)i * 4) = v;      // 8 B coalesced
    }
}

// ---- fused kernel: MFMA phase A (x.U), tiny reduce, MFMA phase B (h.V) ----
// R5 structure, the session's best (73.5 us). Simplicity is load-bearing:
// every added pipeline mechanism (DMA rings, vmcnt schedules, crews,
// interleave) cost more than it recovered. Phase A runs at the measured
// ~3.2 TB/s read-stream ceiling; phase B at the write ceiling with L3-served
// residual reads. ~8% above the measured-ceiling floor -> declared roofline.
__global__ __launch_bounds__(NT, 4) void arl_fused(
    const float* __restrict__ x,  const f16* __restrict__ Ub,
    const f16* __restrict__ Vb,   const float* __restrict__ S,
    const float* __restrict__ gamma, float* __restrict__ out)
{
    const int t   = threadIdx.x;
    const int w   = t >> 6;
    const int l   = t & 63;
    const int n   = l & 15;     // row (A-frag) / col (B,D-frags)
    const int blk = l >> 4;     // k-block / D row-group
    const size_t row0 = (size_t)blockIdx.x * BM;

    __shared__ float s_hacc[NWAVE][16][17];   // +1 pad: conflict-free combine
    __shared__ float s_ssq[NWAVE][16];
    __shared__ __align__(8) f16 s_hh[16][16];

    // ================= Phase A: acc[m][q] += x[m][k]*U'[k][q] =================
    // lane reads row (row0+n), k = w*512 + kb*32 + blk*8 + [0,8)  -> 32 B/lane
    const float* xlane = x + (row0 + n) * DIM + w * KSLICE + blk * 8;
    const half8* UbW   = (const half8*)Ub + (size_t)w * NKB * 64 + l;

    floatx4 acc = {0.f, 0.f, 0.f, 0.f};
    float ssq = 0.f;

    float4 xa0 = *(const float4*)(xlane);
    float4 xa1 = *(const float4*)(xlane + 4);
    half8  ub  = UbW[0];

    #pragma unroll 1
    for (int kb = 0; kb < NKB; ++kb) {
        const int kn = (kb + 1) & (NKB - 1);          // wraps on last iter (harmless)
        float4 nx0 = *(const float4*)(xlane + kn * 32);
        float4 nx1 = *(const float4*)(xlane + kn * 32 + 4);
        half8  nub = UbW[(size_t)kn * 64];
        // fp32 ssq from the exact x values
        ssq = fmaf(xa0.x, xa0.x, ssq); ssq = fmaf(xa0.y, xa0.y, ssq);
        ssq = fmaf(xa0.z, xa0.z, ssq); ssq = fmaf(xa0.w, xa0.w, ssq);
        ssq = fmaf(xa1.x, xa1.x, ssq); ssq = fmaf(xa1.y, xa1.y, ssq);
        ssq = fmaf(xa1.z, xa1.z, ssq); ssq = fmaf(xa1.w, xa1.w, ssq);
        // f16 A-fragment
        half8 a;
        a[0] = (f16)xa0.x; a[1] = (f16)xa0.y; a[2] = (f16)xa0.z; a[3] = (f16)xa0.w;
        a[4] = (f16)xa1.x; a[5] = (f16)xa1.y; a[6] = (f16)xa1.z; a[7] = (f16)xa1.w;
        acc = __builtin_amdgcn_mfma_f32_16x16x32_f16(a, ub, acc, 0, 0, 0);
        xa0 = nx0; xa1 = nx1; ub = nub;
    }

    // ssq: sum the 4 k-block lane groups sharing a row (lanes l, l^16, l^32, l^48)
    ssq += __shfl_xor(ssq, 16, 64);
    ssq += __shfl_xor(ssq, 32, 64);
    if (l < 16) s_ssq[w][l] = ssq;

    // spill C-fragment: D[m = blk*4+j][q = n]
    #pragma unroll
    for (int j = 0; j < 4; ++j) s_hacc[w][blk * 4 + j][n] = acc[j];
    __syncthreads();

    // ============ combine waves; fold rstd + S*keep; publish h (f16) ============
    if (t < 256) {
        const int m = t >> 4, q = t & 15;
        float hsum = 0.f, tssq = 0.f;
        #pragma unroll
        for (int ww = 0; ww < NWAVE; ++ww) {
            hsum += s_hacc[ww][m][q];
            tssq += s_ssq[ww][m];
        }
        const float rstd = rsqrtf(tssq * (1.0f / DIM) + 1e-6f);
        float tot = 0.f;
        #pragma unroll
        for (int i = 0; i < RANK; ++i) tot += fabsf(S[i]);
        const float denom = fmaxf(tot, 1e-8f);
        float cum = 0.f, se = 0.f;
        #pragma unroll
        for (int i = 0; i < RANK; ++i) {
            if (i == q) se = ((cum / denom) < 0.95f) ? S[i] : 0.f;
            cum += fabsf(S[i]);
        }
        s_hh[m][q] = (f16)(hsum * se * rstd);
    }
    __syncthreads();

    // ================= Phase B: out = x + gamma * (h . V) =================
    // A-frag (h) is loop-invariant: lane holds h[n][blk*4 .. +4)
    const half4 ah = *(const half4*)&s_hh[n][blk * 4];
    const half4* Vb4 = (const half4*)Vb;
    const floatx4 zero = {0.f, 0.f, 0.f, 0.f};

    #pragma unroll 2
    for (int i = 0; i < NCB; ++i) {
        const int cb = w * NCB + i;
        const int c0 = cb * 16;
        const half4 bv = Vb4[(size_t)cb * 64 + l];          // 8 B coalesced, L2-hot
        floatx4 d = __builtin_amdgcn_mfma_f32_16x16x16f16(ah, bv, zero, 0, 0, 0);
        const float g = gamma[c0 + n];
        const float* xr  = x   + (row0 + blk * 4) * DIM + c0 + n;   // L3-hot (phase A)
        float*       orr = out + (row0 + blk * 4) * DIM + c0 + n;
        #pragma unroll
        for (int j = 0; j < 4; ++j) {
            const float xv = xr[(size_t)j * DIM];
            __builtin_nontemporal_store(fmaf(g, d[j], xv), orr + (size_t)j * DIM);
        }
    }
}

extern "C" void kernel_launch(void* const* d_in, const int* in_sizes, int n_in,
                              void* d_out, int out_size, void* d_ws, size_t ws_size,
                              hipStream_t stream) {
    (void)in_sizes; (void)n_in; (void)ws_size;
    const float* x  = (const float*)d_in[0];
    const float* U  = (const float*)d_in[1];
    const float* S  = (const float*)d_in[2];
    const float* V  = (const float*)d_in[3];
    const float* nw = (const float*)d_in[4];
    const float* g  = (const float*)d_in[5];
    float* out = (float*)d_out;
    f16* Ub = (f16*)d_ws;                          // 128 KB fragment-order U'
    f16* Vb = (f16*)((char*)d_ws + 128 * 1024);    // 128 KB fragment-order V

    hipLaunchKernelGGL(prep_weights, dim3(64), dim3(256), 0, stream,
                       U, nw, V, Ub, Vb);

    const int rows = out_size / DIM;               // 8192
    const int grid = rows / BM;                    // 512
    hipLaunchKernelGGL(arl_fused, dim3(grid), dim3(NT), 0, stream,
                       x, Ub, Vb, S, g, out);
}